// Round 5
// baseline (63283.716 us; speedup 1.0000x reference)
//
#include <hip/hip_runtime.h>
#include <cstdio>

// ---------------- dims ----------------
static constexpr int cB = 32, cTENC = 256, cENCD = 512, cTDEC = 500, cMEL = 80,
    cNSTEP = 250, cPRE = 256, cAD = 128, cAR = 1024, cDR = 1024, cFLT = 32,
    cKSZ = 31, cPADC = 15, cNG = 4096;
static constexpr int cKA = cPRE + cENCD + cAR;   // 1792 : [x | ctx | h_a]
static constexpr int cKD = cAR + cENCD + cDR;    // 2560 : [h_a | ctx | dec_h]
static constexpr int cKM = cDR + cENCD;          // 1536 : [dec_h | ctx]
static constexpr int cNMP = 192;                 // padded 161 (160 mel + 1 stop)
static constexpr int cNSA = 14;                  // attn k-splits (span 128)
static constexpr int cNSD = 16;                  // dec  k-splits (span 160)
static constexpr int cRDA = 128;                 // attn LDS-resident rows (all)
static constexpr int cRDD = 132;                 // dec LDS-resident rows (of 160)
// dynamic LDS: dec = 132*1024 + 160*36*4 = 135168 + 23040 = 158208 (max)
static constexpr int cDYN = 158208;

typedef unsigned short ushortT;
typedef unsigned int uintT;
typedef unsigned long long ullT;

// ---------------- output layout (floats) ----------------
static constexpr size_t MEL_OFF = 0;
static constexpr size_t STOP_OFF = (size_t)cB * cTDEC * cMEL;      // 1,280,000
static constexpr size_t ATT_OFF = STOP_OFF + (size_t)cB * cTDEC;   // 1,296,000

// ---------------- workspace layout (float units) ----------------
static constexpr size_t WS_WATB = 0;                                   // us[1792][4096]
static constexpr size_t WS_WDTB = WS_WATB + (size_t)cKA * cNG / 2;     // us[2560][4096]
static constexpr size_t WS_WMT  = WS_WDTB + (size_t)cKD * cNG / 2;     // f[1536][192]
static constexpr size_t WS_WQT  = WS_WMT  + (size_t)cKM * cNMP;        // f[1024][128]
static constexpr size_t WS_WMTR = WS_WQT  + (size_t)cAR * cAD;         // f[512][128]
static constexpr size_t WS_PM   = WS_WMTR + (size_t)cENCD * cAD;       // f[32][256][128]
static constexpr size_t WS_XPRE = WS_PM   + (size_t)cB * cTENC * cAD;  // f[250][32][256] = [n][b][j]
static constexpr size_t WS_XA   = WS_XPRE + (size_t)cNSTEP * cPRE * cB;// f[2][32][1792] = [buf][b][k]
static constexpr size_t WS_XD   = WS_XA   + (size_t)2 * cKA * cB;      // f[32][2560] = [b][k]
static constexpr size_t WS_CA   = WS_XD   + (size_t)cKD * cB;          // f[32][1024]
static constexpr size_t WS_CD   = WS_CA   + (size_t)cB * cAR;          // f[32][1024]
static constexpr size_t WS_CUM  = WS_CD   + (size_t)cB * cDR;          // f[32][256]
static constexpr size_t WS_CTR  = WS_CUM  + (size_t)cB * cTENC;        // u32[128] (8 ctrs x 64B)
static constexpr size_t WS_GA   = WS_CTR  + 128;                       // f[32][14][4096]
static constexpr size_t WS_GD   = WS_GA   + (size_t)cB * cNSA * cNG;   // f[32][16][4096]
static constexpr size_t WS_PROJ = WS_GD   + (size_t)cB * cNSD * cNG;   // f[250][32][1536] = [t][b][k]
static constexpr size_t WS_TOTAL = WS_PROJ + (size_t)cNSTEP * cKM * cB;
// X1 (prenet intermediate) aliases GA/GD region: used only pre-loop.
static constexpr size_t WS_X1   = WS_GA;                               // f[250][32][256]

struct Args {
  const float *enc, *inputs;
  const int *mlen;
  const float *W1, *b1, *W2, *b2, *Wm;
  const float *Wih_a, *Whh_a, *bih_a, *bhh_a;
  const float *Wq, *conv_w, *conv_b, *WL, *v;
  const float *Wih_d, *Whh_d, *bih_d, *bhh_d;
  const float *Wmel, *bmel, *Wstop, *bstop;
  float *out;
  float *ws;
};

struct AttnSh {
  float h[cAR];
  float pq[cAD];
  float cumext[cTENC + 2 * cPADC];
  float eparts[2][cTENC];
  float e[cTENC];
  float sred[16];
  float loc[cFLT * 257];
  float wl[cAD * 33];
  float cw[cFLT * cKSZ];
  float vv[cAD];
};

// ---------- device-coherent (agent-scope, L2-non-dirtying) access ----------
__device__ __forceinline__ float ld_sc(const float* p) {
  return __hip_atomic_load(p, __ATOMIC_RELAXED, __HIP_MEMORY_SCOPE_AGENT);
}
__device__ __forceinline__ void st_sc(float* p, float v) {
  __hip_atomic_store(p, v, __ATOMIC_RELAXED, __HIP_MEMORY_SCOPE_AGENT);
}
__device__ __forceinline__ void st_sc2(float2* p, float x, float y) {
  ullT u = (ullT)__float_as_uint(x) | ((ullT)__float_as_uint(y) << 32);
  __hip_atomic_store((ullT*)p, u, __ATOMIC_RELAXED, __HIP_MEMORY_SCOPE_AGENT);
}

// Distributed monotonic grid barrier: 8 counters, 64B apart.
__device__ __forceinline__ void gbar(uintT* ctrs, uintT ph) {
  __syncthreads();
  if (threadIdx.x == 0)
    __hip_atomic_fetch_add(ctrs + (blockIdx.x & 7) * 16, 1u,
                           __ATOMIC_RELAXED, __HIP_MEMORY_SCOPE_AGENT);
  if (threadIdx.x < 8) {
    const uintT target = ph * 32u;   // 256 WGs / 8 counters
    while (__hip_atomic_load(ctrs + threadIdx.x * 16, __ATOMIC_RELAXED,
                             __HIP_MEMORY_SCOPE_AGENT) < target)
      __builtin_amdgcn_s_sleep(8);
  }
  __syncthreads();
}

__device__ __forceinline__ float sigm_f(float x) { return 1.f / (1.f + __expf(-x)); }
__device__ __forceinline__ float tanh_f(float x) {
  float e = __expf(2.f * x);
  return 1.f - 2.f / (e + 1.f);
}

__device__ __forceinline__ void fma8x4(float (&acc)[8][4], const uint4 w, const float4 x4) {
  float wf[8];
  wf[0] = __uint_as_float(w.x << 16);
  wf[1] = __uint_as_float(w.x & 0xFFFF0000u);
  wf[2] = __uint_as_float(w.y << 16);
  wf[3] = __uint_as_float(w.y & 0xFFFF0000u);
  wf[4] = __uint_as_float(w.z << 16);
  wf[5] = __uint_as_float(w.z & 0xFFFF0000u);
  wf[6] = __uint_as_float(w.w << 16);
  wf[7] = __uint_as_float(w.w & 0xFFFF0000u);
  const float xv[4] = {x4.x, x4.y, x4.z, x4.w};
#pragma unroll
  for (int c = 0; c < 8; ++c)
#pragma unroll
    for (int j = 0; j < 4; ++j) acc[c][j] = fmaf(wf[c], xv[j], acc[c][j]);
}

// One-time weight preload: global slice (rows x 512 cols, row pitch cNG) -> LDS.
static __device__ void preload_w(uint4* dst, const ushortT* src, int rows) {
  const int tid = threadIdx.x;
  for (int i = tid; i < rows * 64; i += 512) {
    const int r = i >> 6, u = i & 63;
    dst[i] = *(const uint4*)(src + (size_t)r * cNG + u * 8);
  }
}

// Batch-32 GEMV partial with LDS-resident weights.
// xT: x base at row offset k0, row stride xstride, layout [b][k].
// wlds: resident rows [0,RD); wstream: global base for rows [RD,KSPAN).
template <int KSPAN, int RD, int NS>
static __device__ void gemv_lds(const ushortT* __restrict__ wlds,
                                const ushortT* __restrict__ wstream,
                                const float* __restrict__ xT, int xstride,
                                float* __restrict__ part,
                                int col0, int slot, float* __restrict__ xs) {
  const int tid = threadIdx.x;
  {
    const int b = tid >> 4, kt = tid & 15;
    const float* src = xT + (size_t)b * xstride;
    for (int k = kt; k < KSPAN; k += 16) xs[k * 36 + b] = ld_sc(src + k);
  }
  __syncthreads();
  const int cq = tid & 63, bq = tid >> 6;
  const ushortT* wl = wlds + cq * 8;
  const float* xp = xs + bq * 4;
  float acc[8][4];
#pragma unroll
  for (int c = 0; c < 8; ++c)
#pragma unroll
    for (int j = 0; j < 4; ++j) acc[c][j] = 0.f;
#pragma unroll 4
  for (int k = 0; k < RD; ++k) {
    const uint4 w = *(const uint4*)(wl + (size_t)k * 512);
    const float4 x4 = *(const float4*)(xp + k * 36);
    fma8x4(acc, w, x4);
  }
  if (RD < KSPAN) {
    const ushortT* wg2 = wstream + cq * 8;
#pragma unroll 4
    for (int k = RD; k < KSPAN; ++k) {
      const uint4 w = *(const uint4*)(wg2 + (size_t)k * cNG);
      const float4 x4 = *(const float4*)(xp + k * 36);
      fma8x4(acc, w, x4);
    }
  }
  const int b0 = bq * 4;
#pragma unroll
  for (int j = 0; j < 4; ++j) {
    float2* dst = (float2*)&part[(((size_t)(b0 + j)) * NS + slot) * cNG + col0 + cq * 8];
    st_sc2(dst + 0, acc[0][j], acc[1][j]);
    st_sc2(dst + 1, acc[2][j], acc[3][j]);
    st_sc2(dst + 2, acc[4][j], acc[5][j]);
    st_sc2(dst + 3, acc[6][j], acc[7][j]);
  }
}

// Decoder LSTM cell for batch b, step s ([b][k] layouts).
static __device__ void dec_cell(const Args& a, float* ws, int b, int s) {
  const int tid = threadIdx.x;
  const float* gd = ws + WS_GD + (size_t)b * cNSD * cNG;
  for (int h = tid; h < cDR; h += 512) {
    float g4[4];
#pragma unroll
    for (int gi = 0; gi < 4; ++gi) {
      const int n = gi * cDR + h;
      float sm = a.bih_d[n] + a.bhh_d[n];
#pragma unroll
      for (int p = 0; p < cNSD; ++p) sm += ld_sc(gd + (size_t)p * cNG + n);
      g4[gi] = sm;
    }
    const float co = ld_sc(ws + WS_CD + (size_t)b * cDR + h);
    const float cn = sigm_f(g4[1]) * co + sigm_f(g4[0]) * tanh_f(g4[2]);
    const float hn = sigm_f(g4[3]) * tanh_f(cn);
    st_sc(ws + WS_CD + (size_t)b * cDR + h, cn);
    st_sc(ws + WS_XD + (size_t)b * cKD + (cAR + cENCD) + h, hn);
    st_sc(ws + WS_PROJ + ((size_t)s * cB + b) * cKM + h, hn);
  }
}

// Attention for batch b at step t ([b][k] layouts).
static __device__ void attn_wg(const Args& a, float* ws, int b, int t,
                               float* __restrict__ xa2, AttnSh& sh) {
  const int tid = threadIdx.x;
  const float* ga = ws + WS_GA + (size_t)b * cNSA * cNG;
  // 1. reduce ga partials + attn LSTM cell
  for (int h = tid; h < cAR; h += 512) {
    float g4[4];
#pragma unroll
    for (int gi = 0; gi < 4; ++gi) {
      const int n = gi * cAR + h;
      float s = a.bih_a[n] + a.bhh_a[n];
#pragma unroll
      for (int p = 0; p < cNSA; ++p) s += ld_sc(ga + (size_t)p * cNG + n);
      g4[gi] = s;
    }
    const float co = ld_sc(ws + WS_CA + (size_t)b * cAR + h);
    const float cn = sigm_f(g4[1]) * co + sigm_f(g4[0]) * tanh_f(g4[2]);
    const float hn = sigm_f(g4[3]) * tanh_f(cn);
    st_sc(ws + WS_CA + (size_t)b * cAR + h, cn);
    sh.h[h] = hn;
    st_sc(xa2 + (size_t)b * cKA + (cPRE + cENCD) + h, hn);
    st_sc(ws + WS_XD + (size_t)b * cKD + h, hn);
  }
  __syncthreads();
  // 2. pq partials (loc as scratch) + small LDS loads
  {
    const int d = tid & 127, kc = tid >> 7;
    float acc = 0.f;
    const float* wq = ws + WS_WQT;
    const int k0 = kc * 256;
    for (int k = k0; k < k0 + 256; ++k) acc = fmaf(sh.h[k], wq[(size_t)k * cAD + d], acc);
    sh.loc[kc * 128 + d] = acc;
  }
  for (int i = tid; i < cAD * 33; i += 512) {
    const int dd = i / 33, f = i - dd * 33;
    sh.wl[i] = (f < cFLT) ? a.WL[dd * cFLT + f] : 0.f;
  }
  for (int i = tid; i < cFLT * cKSZ; i += 512) sh.cw[i] = a.conv_w[i];
  if (tid < cAD) sh.vv[tid] = a.v[tid];
  if (tid < cTENC) sh.cumext[cPADC + tid] = ld_sc(ws + WS_CUM + (size_t)b * cTENC + tid);
  if (tid < 2 * cPADC) sh.cumext[tid < cPADC ? tid : cTENC + tid] = 0.f;
  __syncthreads();
  if (tid < cAD)
    sh.pq[tid] = sh.loc[tid] + sh.loc[128 + tid] + sh.loc[256 + tid] + sh.loc[384 + tid];
  __syncthreads();
  // 3. conv31 over cum
  for (int i = tid; i < cFLT * cTENC; i += 512) {
    const int f = i >> 8, te = i & 255;
    float s = a.conv_b[f];
#pragma unroll
    for (int j = 0; j < cKSZ; ++j) s = fmaf(sh.cumext[te + j], sh.cw[f * cKSZ + j], s);
    sh.loc[f * 257 + te] = s;
  }
  __syncthreads();
  // 4. energies
  {
    const int d = tid & 127, tq = tid >> 7, wv = tid >> 6;
    float wlr[cFLT];
#pragma unroll
    for (int f = 0; f < cFLT; ++f) wlr[f] = sh.wl[d * 33 + f];
    const float pqd = sh.pq[d], vd = sh.vv[d];
    const float* pmb = ws + WS_PM + (size_t)b * cTENC * cAD;
    for (int tt = 0; tt < cTENC / 4; ++tt) {
      const int te = tt * 4 + tq;
      float s = pqd + pmb[(size_t)te * cAD + d];
#pragma unroll
      for (int f = 0; f < cFLT; ++f) s = fmaf(sh.loc[f * 257 + te], wlr[f], s);
      float p = tanh_f(s) * vd;
#pragma unroll
      for (int off = 32; off > 0; off >>= 1) p += __shfl_xor(p, off, 64);
      if ((tid & 63) == 0) sh.eparts[wv & 1][te] = p;
    }
  }
  __syncthreads();
  // 5. mask + softmax over 256
  const int mlen = a.mlen[b];
  if (tid < cTENC) {
    float ev = sh.eparts[0][tid] + sh.eparts[1][tid];
    if (tid >= mlen) ev = -1e9f;
    sh.e[tid] = ev;
  }
  __syncthreads();
  const int wv = tid >> 6;
  {
    float xv = sh.e[tid & 255];
#pragma unroll
    for (int off = 32; off > 0; off >>= 1) xv = fmaxf(xv, __shfl_xor(xv, off, 64));
    if ((tid & 63) == 0) sh.sred[wv] = xv;
  }
  __syncthreads();
  float m = sh.sred[0];
#pragma unroll
  for (int i = 1; i < 8; ++i) m = fmaxf(m, sh.sred[i]);
  const float pex = (tid < cTENC) ? __expf(sh.e[tid] - m) : 0.f;
  {
    float sv = pex;
#pragma unroll
    for (int off = 32; off > 0; off >>= 1) sv += __shfl_xor(sv, off, 64);
    if ((tid & 63) == 0) sh.sred[8 + wv] = sv;
  }
  __syncthreads();
  float ssum = 0.f;
#pragma unroll
  for (int i = 0; i < 8; ++i) ssum += sh.sred[8 + i];
  const float rs = 1.f / ssum;
  if (tid < cTENC) {
    const float al = pex * rs;
    sh.e[tid] = al;
    a.out[ATT_OFF + ((size_t)b * cNSTEP + t) * cTENC + tid] = al;
    st_sc(ws + WS_CUM + (size_t)b * cTENC + tid, sh.cumext[cPADC + tid] + al);
  }
  __syncthreads();
  // 6. ctx = align @ encoder_outputs[b]
  {
    const int k = tid;   // 512 = ENCD
    float acc = 0.f;
    const float* encb = a.enc + (size_t)b * cTENC * cENCD + k;
    for (int te = 0; te < cTENC; ++te) acc = fmaf(sh.e[te], encb[(size_t)te * cENCD], acc);
    st_sc(xa2 + (size_t)b * cKA + cPRE + k, acc);
    st_sc(ws + WS_XD + (size_t)b * cKD + cAR + k, acc);
    st_sc(ws + WS_PROJ + ((size_t)t * cB + b) * cKM + cDR + k, acc);
  }
  __syncthreads();
}

// Post-loop batched mel/stop projection (plain loads; PROJ layout [t][b][k]).
static __device__ void mel_proj(const Args& a, float* ws, float* melred) {
  const int tid = threadIdx.x;
  const int c = tid & 255, sub = tid >> 8;
  for (int t = blockIdx.x; t < cNSTEP; t += gridDim.x) {
    float acc[cB];
#pragma unroll
    for (int b = 0; b < cB; ++b) acc[b] = 0.f;
    if (c < 161) {
      const float* wmt = ws + WS_WMT;
      const float* xr0 = ws + WS_PROJ + (size_t)t * cB * cKM;
      const int k0 = sub * 768;
      for (int k = k0; k < k0 + 768; ++k) {
        const float w = wmt[(size_t)k * cNMP + c];
#pragma unroll
        for (int b = 0; b < cB; ++b) acc[b] = fmaf(w, xr0[(size_t)b * cKM + k], acc[b]);
      }
    }
    __syncthreads();
    if (sub == 1 && c < 161) {
#pragma unroll
      for (int b = 0; b < cB; ++b) melred[b * 164 + c] = acc[b];
    }
    __syncthreads();
    if (sub == 0 && c < 161) {
      if (c < 160) {
        const int fr = c / 80, mm = c % 80;
        const float bm = a.bmel[c];
#pragma unroll
        for (int b = 0; b < cB; ++b) {
          const float val = acc[b] + melred[b * 164 + c] + bm;
          a.out[MEL_OFF + ((size_t)b * cTDEC + (2 * t + fr)) * cMEL + mm] = val;
        }
      } else {
        const float bs = a.bstop[0];
#pragma unroll
        for (int b = 0; b < cB; ++b) {
          const float sp = sigm_f(acc[b] + melred[b * 164 + c] + bs);
          a.out[STOP_OFF + (size_t)b * cTDEC + 2 * t] = sp;
          a.out[STOP_OFF + (size_t)b * cTDEC + 2 * t + 1] = sp;
        }
      }
    }
    __syncthreads();
  }
}

// ---------------- setup kernels ----------------
__device__ __forceinline__ ushortT f2b(float f) {
  const uintT u = __float_as_uint(f);
  return (ushortT)((u + 0x7FFFu + ((u >> 16) & 1u)) >> 16);   // RNE
}

__global__ void k_transpose(const float* __restrict__ src, float* __restrict__ dst,
                            int N, int K, int dpitch) {
  __shared__ float tile[64][65];
  const int tkn = K >> 6;
  const int tk = blockIdx.x % tkn, tn = blockIdx.x / tkn;
  const int c = threadIdx.x & 63, r4 = threadIdx.x >> 6;
  const int n0 = tn << 6, k0 = tk << 6;
#pragma unroll
  for (int rr = 0; rr < 16; ++rr) {
    const int r = r4 * 16 + rr;
    tile[r][c] = src[(size_t)(n0 + r) * K + k0 + c];
  }
  __syncthreads();
#pragma unroll
  for (int rr = 0; rr < 16; ++rr) {
    const int r = r4 * 16 + rr;
    dst[(size_t)(k0 + r) * dpitch + n0 + c] = tile[c][r];
  }
}

__global__ void k_transpose_b16(const float* __restrict__ src, ushortT* __restrict__ dst,
                                int N, int K, int dpitch) {
  __shared__ float tile[64][65];
  const int tkn = K >> 6;
  const int tk = blockIdx.x % tkn, tn = blockIdx.x / tkn;
  const int c = threadIdx.x & 63, r4 = threadIdx.x >> 6;
  const int n0 = tn << 6, k0 = tk << 6;
#pragma unroll
  for (int rr = 0; rr < 16; ++rr) {
    const int r = r4 * 16 + rr;
    tile[r][c] = src[(size_t)(n0 + r) * K + k0 + c];
  }
  __syncthreads();
#pragma unroll
  for (int rr = 0; rr < 16; ++rr) {
    const int r = r4 * 16 + rr;
    dst[(size_t)(k0 + r) * dpitch + n0 + c] = f2b(tile[c][r]);
  }
}

__global__ void k_prep_small(Args a) {
  const size_t i = (size_t)blockIdx.x * blockDim.x + threadIdx.x;
  if (i < 128) ((uintT*)(a.ws + WS_CTR))[i] = 0u;   // barrier counters
  if (i >= (size_t)cKM * cNMP) return;
  const int k = (int)(i / cNMP), c = (int)(i % cNMP);
  a.ws[WS_WMT + i] = (c < 160) ? a.Wmel[(size_t)c * cKM + k]
                               : (c == 160 ? a.Wstop[k] : 0.f);
}

__global__ void k_prenet1(Args a) {
  const size_t i = (size_t)blockIdx.x * blockDim.x + threadIdx.x;
  if (i >= (size_t)cNSTEP * cB * cPRE) return;
  const int j = i & 255, b = (i >> 8) & 31, n = (int)(i >> 13);
  float acc = a.b1[j];
  if (n > 0) {
    const float* fr = a.inputs + ((size_t)b * cTDEC + (2 * n - 1)) * cMEL;
    for (int k = 0; k < cMEL; ++k) acc = fmaf(fr[k], a.W1[j * cMEL + k], acc);
  }
  a.ws[WS_X1 + i] = fmaxf(acc, 0.f);   // [n][b][j]
}

__global__ void k_prenet2(Args a) {
  const size_t i = (size_t)blockIdx.x * blockDim.x + threadIdx.x;
  if (i >= (size_t)cNSTEP * cPRE * cB) return;
  const int j = i & 255, b = (i >> 8) & 31, n = (int)(i >> 13);
  float acc = a.b2[j];
  const float* x1 = a.ws + WS_X1 + ((size_t)n * cB + b) * cPRE;
  for (int k = 0; k < cPRE; ++k) acc = fmaf(x1[k], a.W2[j * cPRE + k], acc);
  a.ws[WS_XPRE + ((size_t)n * cB + b) * cPRE + j] = fmaxf(acc, 0.f);   // [n][b][j]
}

__global__ void k_pm(Args a) {
  const size_t i = (size_t)blockIdx.x * blockDim.x + threadIdx.x;
  if (i >= (size_t)cB * cTENC * cAD) return;
  const int d = i & 127, tt = (i >> 7) & 255, b = (int)(i >> 15);
  float acc = 0.f;
  const float* er = a.enc + ((size_t)b * cTENC + tt) * cENCD;
  const float* wt = a.ws + WS_WMTR;
  for (int k = 0; k < cENCD; ++k) acc = fmaf(er[k], wt[(size_t)k * cAD + d], acc);
  a.ws[WS_PM + i] = acc;
}

// ---------------- persistent cooperative loop ----------------
// PhaseA(t) = attn-gates GEMV(t) [WGs 0-111] || dec-gates GEMV(t-1) [112-239]
// PhaseB(t) = attention(t) [240-255, 2 batches] || dec_cell(t-1) [32-63] || x-copy [64-79]
__global__ void __launch_bounds__(512, 1) k_loop(Args a) {
  extern __shared__ char dyn[];
  float* ws = a.ws;
  uintT* ctrs = (uintT*)(ws + WS_CTR);
  const ushortT* watb = (const ushortT*)(ws + WS_WATB);
  const ushortT* wdtb = (const ushortT*)(ws + WS_WDTB);
  const int wg = blockIdx.x;
  const int tid = threadIdx.x;
  uintT ph = 0;

  ushortT* wlds = (ushortT*)dyn;
  AttnSh* at = (AttnSh*)dyn;
  float* melred = (float*)dyn;

  // role geometry
  const int iA = wg, sA = iA >> 3, cbA = iA & 7;               // wg<112
  const int iD = wg - 112, sD = iD >> 3, cbD = iD & 7;         // 112<=wg<240
  const int col0A = cbA * 512, k0A = sA * 128;
  const int col0D = cbD * 512, k0D = sD * 160;
  float* xsA = (float*)(dyn + cRDA * 1024);
  float* xsD = (float*)(dyn + cRDD * 1024);
  const ushortT* wstrD = wdtb + (size_t)k0D * cNG + col0D;

  // ---- one-time weight preload + state init ----
  if (wg < 112) {
    preload_w((uint4*)wlds, watb + (size_t)k0A * cNG + col0A, cRDA);
  } else if (wg < 240) {
    preload_w((uint4*)wlds, wstrD, cRDD);
  }
  float* xa0 = ws + WS_XA;
  if (wg < 32) {
    const int b = wg;
    for (int i = tid; i < cTENC; i += 512) st_sc(ws + WS_CUM + (size_t)b * cTENC + i, 0.f);
    for (int i = tid; i < cAR; i += 512) st_sc(ws + WS_CA + (size_t)b * cAR + i, 0.f);
  } else if (wg < 64) {
    const int b = wg - 32;
    for (int i = tid; i < cDR; i += 512) st_sc(ws + WS_CD + (size_t)b * cDR + i, 0.f);
  } else if (wg < 80) {
    const int i = (wg - 64) * 512 + tid;               // 8192 = B*PRE, [b][j]
    const int b = i >> 8, j = i & 255;
    st_sc(xa0 + (size_t)b * cKA + j, ws[WS_XPRE + i]);
  } else if (wg < 176) {
    const int i = (wg - 80) * 512 + tid;               // 49152 = B*(ENCD+AR)
    const int b = i / 1536, j = i % 1536;
    st_sc(xa0 + (size_t)b * cKA + cPRE + j, 0.f);
  } else if (wg < 240) {
    const int i = (wg - 176) * 512 + tid;              // 32768 = B*DR
    const int b = i >> 10, h = i & 1023;
    st_sc(ws + WS_XD + (size_t)b * cKD + (cAR + cENCD) + h, 0.f);
  }
  ++ph; gbar(ctrs, ph);

  for (int t = 0; t <= cNSTEP; ++t) {
    const float* xa = ws + WS_XA + (size_t)(t & 1) * cKA * cB;
    float* xa2 = ws + WS_XA + (size_t)((t + 1) & 1) * cKA * cB;
    // ---- Phase A ----
    if (wg < 112) {
      if (t < cNSTEP)
        gemv_lds<128, cRDA, cNSA>(wlds, nullptr, xa + k0A, cKA,
                                  ws + WS_GA, col0A, sA, xsA);
    } else if (wg < 240) {
      if (t >= 1)
        gemv_lds<160, cRDD, cNSD>(wlds, wstrD, ws + WS_XD + k0D, cKD,
                                  ws + WS_GD, col0D, sD, xsD);
    }
    ++ph; gbar(ctrs, ph);
    // ---- Phase B ----
    if (wg >= 240) {
      if (t < cNSTEP) {
        attn_wg(a, ws, wg - 240, t, xa2, *at);
        attn_wg(a, ws, wg - 240 + 16, t, xa2, *at);
      }
    } else if (wg >= 32 && wg < 64) {
      if (t >= 1) dec_cell(a, ws, wg - 32, t - 1);
    } else if (wg >= 64 && wg < 80) {
      if (t + 1 < cNSTEP) {
        const int i = (wg - 64) * 512 + tid;   // [b][j]
        const int b = i >> 8, j = i & 255;
        st_sc(xa2 + (size_t)b * cKA + j,
              ws[WS_XPRE + (size_t)(t + 1) * cPRE * cB + i]);
      }
    }
    ++ph; gbar(ctrs, ph);
  }
  mel_proj(a, ws, melred);
}

// ---------------- host ----------------
extern "C" void kernel_launch(void* const* d_in, const int* in_sizes, int n_in,
                              void* d_out, int out_size, void* d_ws, size_t ws_size,
                              hipStream_t stream) {
  (void)in_sizes; (void)n_in; (void)out_size;
  Args a;
  a.enc = (const float*)d_in[0];
  a.inputs = (const float*)d_in[1];
  a.mlen = (const int*)d_in[2];
  a.W1 = (const float*)d_in[3];  a.b1 = (const float*)d_in[4];
  a.W2 = (const float*)d_in[5];  a.b2 = (const float*)d_in[6];
  a.Wm = (const float*)d_in[7];
  a.Wih_a = (const float*)d_in[8];  a.Whh_a = (const float*)d_in[9];
  a.bih_a = (const float*)d_in[10]; a.bhh_a = (const float*)d_in[11];
  a.Wq = (const float*)d_in[12];
  a.conv_w = (const float*)d_in[13]; a.conv_b = (const float*)d_in[14];
  a.WL = (const float*)d_in[15];     a.v = (const float*)d_in[16];
  a.Wih_d = (const float*)d_in[17];  a.Whh_d = (const float*)d_in[18];
  a.bih_d = (const float*)d_in[19];  a.bhh_d = (const float*)d_in[20];
  a.Wmel = (const float*)d_in[21];   a.bmel = (const float*)d_in[22];
  a.Wstop = (const float*)d_in[23];  a.bstop = (const float*)d_in[24];
  a.out = (float*)d_out;
  a.ws = (float*)d_ws;

  if (ws_size < WS_TOTAL * sizeof(float)) {
    fprintf(stderr, "kernel_launch: ws too small: need %zu bytes, have %zu\n",
            WS_TOTAL * sizeof(float), ws_size);
    return;
  }

  float* ws = a.ws;
  ushortT* watb = (ushortT*)(ws + WS_WATB);
  ushortT* wdtb = (ushortT*)(ws + WS_WDTB);
  k_transpose_b16<<<dim3((768 / 64) * (4096 / 64)), dim3(256), 0, stream>>>(
      a.Wih_a, watb, 4096, 768, cNG);
  k_transpose_b16<<<dim3((1024 / 64) * (4096 / 64)), dim3(256), 0, stream>>>(
      a.Whh_a, watb + (size_t)768 * cNG, 4096, 1024, cNG);
  k_transpose_b16<<<dim3((1536 / 64) * (4096 / 64)), dim3(256), 0, stream>>>(
      a.Wih_d, wdtb, 4096, 1536, cNG);
  k_transpose_b16<<<dim3((1024 / 64) * (4096 / 64)), dim3(256), 0, stream>>>(
      a.Whh_d, wdtb + (size_t)1536 * cNG, 4096, 1024, cNG);
  k_transpose<<<dim3((1024 / 64) * (128 / 64)), dim3(256), 0, stream>>>(
      a.Wq, ws + WS_WQT, 128, 1024, cAD);
  k_transpose<<<dim3((512 / 64) * (128 / 64)), dim3(256), 0, stream>>>(
      a.Wm, ws + WS_WMTR, 128, 512, cAD);

  k_prep_small<<<dim3((cKM * cNMP + 255) / 256), dim3(256), 0, stream>>>(a);
  k_prenet1<<<dim3(8000), dim3(256), 0, stream>>>(a);
  k_prenet2<<<dim3(8000), dim3(256), 0, stream>>>(a);
  k_pm<<<dim3(4096), dim3(256), 0, stream>>>(a);

  hipError_t e0 = hipFuncSetAttribute((const void*)k_loop,
                                      hipFuncAttributeMaxDynamicSharedMemorySize, cDYN);
  if (e0 != hipSuccess)
    fprintf(stderr, "kernel_launch: setattr failed: %s\n", hipGetErrorString(e0));

  void* params[] = { (void*)&a };
  hipError_t err = hipLaunchCooperativeKernel((const void*)k_loop, dim3(256), dim3(512),
                                              params, cDYN, stream);
  if (err != hipSuccess) {
    fprintf(stderr, "kernel_launch: cooperative launch failed: %s\n",
            hipGetErrorString(err));
  }
}